// Round 8
// baseline (224.298 us; speedup 1.0000x reference)
//
#include <hip/hip_runtime.h>
#include <math.h>

// Problem constants
#define BB   32
#define CC   512
#define HWN  1024   // H*W
#define MM   77
#define TXT  768
#define NH   8
#define HD   64
#define SCALEF 0.125f   // 1/sqrt(64)
#define MPAD 96          // padded M for PV K-dim (3 x 32)
#define KVROWS (BB*MPAD) // 3072 padded row space for kv gemm
#define PP   104         // Ps pitch in shorts (104*2=208=13*16B, aligned)
#define OSP  132         // Os pitch in floats (multiple of 4 for float4 align)

typedef __attribute__((ext_vector_type(8))) short          bf16x8; // MFMA A/B frag
typedef __attribute__((ext_vector_type(8))) unsigned short us8;
typedef __attribute__((ext_vector_type(4))) float          f32x4;  // MFMA C/D frag

__device__ inline unsigned short f2bf(float f) {
    union { float f; unsigned u; } v; v.f = f;
    unsigned r = v.u + 0x7fff + ((v.u >> 16) & 1);   // RNE
    return (unsigned short)(r >> 16);
}

__device__ inline void gload_lds16(const void* g, void* l) {
    __builtin_amdgcn_global_load_lds(
        (const __attribute__((address_space(1))) void*)g,
        (__attribute__((address_space(3))) void*)l, 16, 0, 0);
}

// ---------------------------------------------------------------------------
// prep: block-id partitioned.
//  bid < 4096 : x[b,c,n] -> xT[b,n,c] bf16 (64x64 LDS transpose tiles)
//  bid >= 4096: flat fp32->bf16 converts of Wq | Wk | Wv | text_emb
// ---------------------------------------------------------------------------
#define TGRID 4096                   // 16 * 8 * 32 transpose blocks
#define CV_WQ 65536                  // 512*512/4 float4s
#define CV_WK 98304                  // 512*768/4
#define CV_WV 98304
#define CV_TE 473088                 // 2464*768/4
#define CVTOT (CV_WQ + CV_WK + CV_WV + CV_TE)   // 735232 = 2872 * 256

__global__ __launch_bounds__(256) void prep_kernel(
    const float* __restrict__ x, const float* __restrict__ te,
    const float* __restrict__ Wq, const float* __restrict__ Wk,
    const float* __restrict__ Wv,
    unsigned short* __restrict__ xT, unsigned short* __restrict__ teb,
    unsigned short* __restrict__ Wqb, unsigned short* __restrict__ Wkb,
    unsigned short* __restrict__ Wvb)
{
    const int bid = blockIdx.x;
    const int t = threadIdx.x;

    if (bid < TGRID) {
        // ---- transpose+convert x ----
        const int nt = bid & 15, ct = (bid >> 4) & 7, b = bid >> 7;
        const int n0 = nt * 64, c0 = ct * 64;
        __shared__ float tile[64][65];
        const float* xb = x + (size_t)b * CC * HWN;
        {
            const int c = t >> 2;
            #pragma unroll
            for (int j = 0; j < 4; ++j) {
                const int f4 = (t & 3) + j * 4;
                const float4 v = *(const float4*)&xb[(size_t)(c0 + c) * HWN + n0 + f4 * 4];
                tile[c][f4 * 4 + 0] = v.x; tile[c][f4 * 4 + 1] = v.y;
                tile[c][f4 * 4 + 2] = v.z; tile[c][f4 * 4 + 3] = v.w;
            }
        }
        __syncthreads();
        unsigned short* xTb = xT + (size_t)b * HWN * CC;
        #pragma unroll
        for (int j = 0; j < 2; ++j) {
            const int n = (t >> 3) + j * 32;
            const int c8 = (t & 7) * 8;
            us8 o;
            #pragma unroll
            for (int i = 0; i < 8; ++i) o[i] = f2bf(tile[c8 + i][n]);
            *(us8*)&xTb[(size_t)(n0 + n) * CC + c0 + c8] = o;
        }
    } else {
        // ---- flat converts ----
        const int idx = (bid - TGRID) * 256 + t;   // float4 index, < CVTOT
        const float* src; unsigned short* dst; int off;
        if (idx < CV_WQ)                    { src = Wq; dst = Wqb; off = idx; }
        else if (idx < CV_WQ + CV_WK)       { src = Wk; dst = Wkb; off = idx - CV_WQ; }
        else if (idx < CV_WQ + CV_WK + CV_WV) { src = Wv; dst = Wvb; off = idx - CV_WQ - CV_WK; }
        else                                { src = te; dst = teb; off = idx - CV_WQ - CV_WK - CV_WV; }
        const float4 v = ((const float4*)src)[off];
        ushort4 o;
        o.x = f2bf(v.x); o.y = f2bf(v.y); o.z = f2bf(v.z); o.w = f2bf(v.w);
        ((ushort4*)dst)[off] = o;
    }
}

// ---------------------------------------------------------------------------
// gemm_all: merged Q-GEMM + K/V-GEMM. 256x128 tiles, BK=32, 8 waves (4x2),
// each wave owns a 64x64 output sub-tile (4x4 16x16x32 MFMAs).
// Same proven schedule as the 128x128 version (r6): 3-buffer LDS, 2-deep
// prefetch, counted vmcnt with WAIT-BEFORE-BARRIER:
//   per iter: s_waitcnt vmcnt(3) -> s_barrier -> stage(k+2) -> compute k
// Per wave per iter: 2 A-loads + 1 B-load (3 own loads/tile -> vmcnt(3)
// steady state, vmcnt(0) on the last tile). Bigger tile raises FLOP/staged-
// byte 64 -> 87 and halves barriers per output FLOP vs 128x128.
// LDS: As 3x16KB + Bs 3x8KB = 72 KB -> 2 blocks/CU; VGPR capped at 128 via
// __launch_bounds__(512, 4) (r6 compiled at 124 with identical wave state).
//  bid < 96            : K/V = teb . W^T + bias     -> Kb / Vt (transposed)
//  bid >= 96           : Q = xT . Wqb^T + bq        -> Qb bf16 [32768][512]
// (K/V first: 24 K-iters vs Q's 16 -> longest blocks launch first)
// ---------------------------------------------------------------------------
__global__ __launch_bounds__(512, 4) void gemm_all(
    const unsigned short* __restrict__ xT, const unsigned short* __restrict__ Wqb,
    const float* __restrict__ bq, unsigned short* __restrict__ Qb,
    const unsigned short* __restrict__ teb,
    const unsigned short* __restrict__ Wkb, const float* __restrict__ bk,
    const unsigned short* __restrict__ Wvb, const float* __restrict__ bv,
    unsigned short* __restrict__ Kb, unsigned short* __restrict__ Vt)
{
    const int bid = blockIdx.x;
    __shared__ unsigned short As[3][256 * 32];   // 16 KB per buffer
    __shared__ unsigned short Bs[3][128 * 32];   // 8 KB per buffer
    const int t = threadIdx.x;
    const int lane = t & 63, w = t >> 6;         // w = 0..7
    const int wr = w >> 1, wc = w & 1;           // 4x2 wave grid
    const int lm = lane & 15, quad = lane >> 4;
    const int lrow = lane >> 2, lk = (lane & 3) * 8;

    const unsigned short *gA0, *gA1, *gB;
    int kIters, mode, row0, co0;

    if (bid >= 96) {
        const int qb = bid - 96;            // 0..511
        mode = 0;
        const int rt = qb & 127, ct = qb >> 7;
        row0 = rt * 256; co0 = ct * 128;
        kIters = CC / 32;
        gA0 = xT  + (size_t)(row0 + (w * 2 + 0) * 16 + lrow) * CC + lk;
        gA1 = xT  + (size_t)(row0 + (w * 2 + 1) * 16 + lrow) * CC + lk;
        gB  = Wqb + (size_t)(co0 + w * 16 + lrow) * CC + lk;
    } else {
        const int id = bid;                 // 0..95
        const int rt = id % 12, cc = id / 12;
        const int isV = (cc >= 4);
        mode = isV ? 2 : 1;
        row0 = rt * 256; co0 = (cc & 3) * 128;
        kIters = TXT / 32;
        const unsigned short* Wb = isV ? Wvb : Wkb;
        const int rp0 = row0 + (w * 2 + 0) * 16 + lrow;
        const int rp1 = row0 + (w * 2 + 1) * 16 + lrow;
        const int b0i = rp0 / MPAD, m0i = min(rp0 % MPAD, MM - 1);
        const int b1i = rp1 / MPAD, m1i = min(rp1 % MPAD, MM - 1);
        gA0 = teb + (size_t)(b0i * MM + m0i) * TXT + lk;
        gA1 = teb + (size_t)(b1i * MM + m1i) * TXT + lk;
        gB  = Wb + (size_t)(co0 + w * 16 + lrow) * TXT + lk;
    }

    f32x4 acc[4][4] = {};

    const int lA0 = (w * 2 + 0) * 512, lA1 = (w * 2 + 1) * 512, lB = w * 512;

    // prologue: stage tile 0 -> buf0, tile 1 -> buf1 (6 own loads outstanding)
    gload_lds16(gA0, &As[0][lA0]);
    gload_lds16(gA1, &As[0][lA1]);
    gload_lds16(gB,  &Bs[0][lB]);
    gload_lds16(gA0 + 32, &As[1][lA0]);
    gload_lds16(gA1 + 32, &As[1][lA1]);
    gload_lds16(gB + 32,  &Bs[1][lB]);

    int cb = 0;                       // buffer holding tile k
    for (int k = 0; k < kIters; ++k) {
        // retire MY tile-k loads (tile k+1's 3 stay in flight), THEN join:
        // after the barrier, every wave's tile-k rows are in LDS.
        if (k + 1 < kIters) {
            asm volatile("s_waitcnt vmcnt(3)" ::: "memory");
        } else {
            asm volatile("s_waitcnt vmcnt(0)" ::: "memory");
        }
        __builtin_amdgcn_s_barrier();
        __builtin_amdgcn_sched_barrier(0);

        // stage tile k+2 into buf (cb+2)%3 (tile k-1's buffer; all waves'
        // reads of it completed before they arrived at the barrier above)
        if (k + 2 < kIters) {
            const int nb = (cb >= 1) ? cb - 1 : 2;   // (cb+2)%3
            gload_lds16(gA0 + (k + 2) * 32, &As[nb][lA0]);
            gload_lds16(gA1 + (k + 2) * 32, &As[nb][lA1]);
            gload_lds16(gB + (k + 2) * 32,  &Bs[nb][lB]);
        }

        bf16x8 a[4], bfr[4];
        #pragma unroll
        for (int i = 0; i < 4; ++i)
            a[i] = *(const bf16x8*)&As[cb][(wr * 64 + i * 16 + lm) * 32 + quad * 8];
        #pragma unroll
        for (int i = 0; i < 4; ++i)
            bfr[i] = *(const bf16x8*)&Bs[cb][(wc * 64 + i * 16 + lm) * 32 + quad * 8];
        #pragma unroll
        for (int mi = 0; mi < 4; ++mi)
            #pragma unroll
            for (int ni = 0; ni < 4; ++ni)
                acc[mi][ni] = __builtin_amdgcn_mfma_f32_16x16x32_bf16(
                    a[mi], bfr[ni], acc[mi][ni], 0, 0, 0);

        cb = (cb >= 2) ? 0 : cb + 1;
    }

    if (mode == 0) {
        #pragma unroll
        for (int ni = 0; ni < 4; ++ni) {
            const int col = co0 + wc * 64 + ni * 16 + lm;
            const float bias = bq[col];
            #pragma unroll
            for (int mi = 0; mi < 4; ++mi) {
                #pragma unroll
                for (int j = 0; j < 4; ++j) {
                    const int row = row0 + wr * 64 + mi * 16 + quad * 4 + j;
                    Qb[(size_t)row * CC + col] = f2bf(acc[mi][ni][j] + bias);
                }
            }
        }
    } else {
        const float* bias_p = (mode == 2) ? bv : bk;
        #pragma unroll
        for (int ni = 0; ni < 4; ++ni) {
            const int col = co0 + wc * 64 + ni * 16 + lm;
            const float bias = bias_p[col];
            #pragma unroll
            for (int mi = 0; mi < 4; ++mi) {
                #pragma unroll
                for (int j = 0; j < 4; ++j) {
                    const int row = row0 + wr * 64 + mi * 16 + quad * 4 + j;
                    const int bo = row / MPAD, mo = row % MPAD;
                    const unsigned short hv = f2bf(acc[mi][ni][j] + bias);
                    if (mode == 2) {
                        Vt[((size_t)bo * CC + col) * MPAD + mo] = hv;
                    } else if (mo < MM) {
                        Kb[((size_t)bo * MM + mo) * CC + col] = hv;
                    }
                }
            }
        }
    }
}

// ---------------------------------------------------------------------------
// MFMA attention: block = (128 Q rows, head h, batch b). QK^T via mfma,
// softmax in C-layout regs, exp(P)->LDS (A-layout bf16), PV via mfma,
// epilogue transposed through LDS -> coalesced float4 stores along n.
// ---------------------------------------------------------------------------
__global__ __launch_bounds__(256) void attn_mfma(
    const unsigned short* __restrict__ Qb, const unsigned short* __restrict__ Kb,
    const unsigned short* __restrict__ Vt, const int* __restrict__ amask,
    float* __restrict__ out)
{
    const int ntile = blockIdx.x;   // 0..7
    const int h     = blockIdx.y;   // 0..7
    const int b     = blockIdx.z;   // 0..31
    const int row0  = ntile * 128;

    __shared__ char smem[64 * OSP * 4];   // Ps then Os (unioned)
    __shared__ float msk[80];
    unsigned short* Ps = (unsigned short*)smem;
    float* Os = (float*)smem;

    const int t = threadIdx.x;
    const int w = t >> 6, lane = t & 63;
    const int lm = lane & 15, quad = lane >> 4;

    {
        const int r = t >> 1, off = 80 + (t & 1) * 8;
        us8 z = {0, 0, 0, 0, 0, 0, 0, 0};
        *(us8*)&Ps[r * PP + off] = z;
    }
    if (t < 80) msk[t] = (t < MM && amask[b * MM + t] != 0) ? 0.f : -INFINITY;
    __syncthreads();

    // ---- Phase 1: scores = Q K^T ----
    f32x4 s[2][5] = {};
    const unsigned short* qbase = Qb + ((size_t)b * HWN + row0) * CC + h * HD;
    const unsigned short* kbase = Kb + (size_t)b * MM * CC + h * HD;
    #pragma unroll
    for (int ks = 0; ks < 2; ++ks) {
        bf16x8 a[2], kf[5];
        #pragma unroll
        for (int mt = 0; mt < 2; ++mt)
            a[mt] = *(const bf16x8*)&qbase[(size_t)((w * 2 + mt) * 16 + lm) * CC + ks * 32 + quad * 8];
        #pragma unroll
        for (int n = 0; n < 5; ++n) {
            const int kr = min(n * 16 + lm, MM - 1);
            kf[n] = *(const bf16x8*)&kbase[(size_t)kr * CC + ks * 32 + quad * 8];
        }
        #pragma unroll
        for (int mt = 0; mt < 2; ++mt)
            #pragma unroll
            for (int n = 0; n < 5; ++n)
                s[mt][n] = __builtin_amdgcn_mfma_f32_16x16x32_bf16(a[mt], kf[n], s[mt][n], 0, 0, 0);
    }

    // ---- Phase 2: masked softmax per row ----
    float inv[2][4];
    #pragma unroll
    for (int mt = 0; mt < 2; ++mt) {
        #pragma unroll
        for (int j = 0; j < 4; ++j) {
            float v[5];
            #pragma unroll
            for (int n = 0; n < 5; ++n)
                v[n] = s[mt][n][j] * SCALEF + msk[n * 16 + lm];
            float mx = fmaxf(fmaxf(fmaxf(v[0], v[1]), fmaxf(v[2], v[3])), v[4]);
            mx = fmaxf(mx, __shfl_xor(mx, 1, 64));
            mx = fmaxf(mx, __shfl_xor(mx, 2, 64));
            mx = fmaxf(mx, __shfl_xor(mx, 4, 64));
            mx = fmaxf(mx, __shfl_xor(mx, 8, 64));
            float sum = 0.f;
            #pragma unroll
            for (int n = 0; n < 5; ++n) { v[n] = __expf(v[n] - mx); sum += v[n]; }
            sum += __shfl_xor(sum, 1, 64);
            sum += __shfl_xor(sum, 2, 64);
            sum += __shfl_xor(sum, 4, 64);
            sum += __shfl_xor(sum, 8, 64);
            inv[mt][j] = 1.0f / sum;
            const int mrow = (w * 2 + mt) * 16 + quad * 4 + j;
            #pragma unroll
            for (int n = 0; n < 5; ++n)
                Ps[mrow * PP + n * 16 + lm] = f2bf(v[n]);
        }
    }
    __syncthreads();

    // ---- Phase 3: O = P V ----
    f32x4 o[2][4] = {};
    const unsigned short* vbase = Vt + ((size_t)b * CC + h * HD) * MPAD;
    #pragma unroll
    for (int ks = 0; ks < 3; ++ks) {
        bf16x8 a[2], vf[4];
        #pragma unroll
        for (int mt = 0; mt < 2; ++mt)
            a[mt] = *(const bf16x8*)&Ps[((w * 2 + mt) * 16 + lm) * PP + ks * 32 + quad * 8];
        #pragma unroll
        for (int n = 0; n < 4; ++n)
            vf[n] = *(const bf16x8*)&vbase[(size_t)(n * 16 + lm) * MPAD + ks * 32 + quad * 8];
        #pragma unroll
        for (int mt = 0; mt < 2; ++mt)
            #pragma unroll
            for (int n = 0; n < 4; ++n)
                o[mt][n] = __builtin_amdgcn_mfma_f32_16x16x32_bf16(a[mt], vf[n], o[mt][n], 0, 0, 0);
    }
    __syncthreads();   // Ps fully consumed; smem becomes Os

    // ---- Epilogue 1: scaled O -> Os[col][r], float4 LDS writes ----
    #pragma unroll
    for (int mt = 0; mt < 2; ++mt) {
        #pragma unroll
        for (int n = 0; n < 4; ++n) {
            const int col = n * 16 + lm;
            const int r0 = (w * 2 + mt) * 16 + quad * 4;
            float4 st;
            st.x = o[mt][n][0] * inv[mt][0];
            st.y = o[mt][n][1] * inv[mt][1];
            st.z = o[mt][n][2] * inv[mt][2];
            st.w = o[mt][n][3] * inv[mt][3];
            *(float4*)&Os[col * OSP + r0] = st;
        }
    }
    __syncthreads();

    // ---- Epilogue 2: coalesced float4 stores, contiguous in n ----
    float* obase = out + ((size_t)b * CC + h * HD) * HWN + row0;
    #pragma unroll
    for (int p = 0; p < 8; ++p) {
        const int idx = p * 256 + t;
        const int col = idx >> 5;
        const int r4  = idx & 31;
        const float4 v = *(const float4*)&Os[col * OSP + r4 * 4];
        *(float4*)&obase[(size_t)col * HWN + r4 * 4] = v;
    }
}

extern "C" void kernel_launch(void* const* d_in, const int* in_sizes, int n_in,
                              void* d_out, int out_size, void* d_ws, size_t ws_size,
                              hipStream_t stream)
{
    const float* x     = (const float*)d_in[0];
    const float* te    = (const float*)d_in[1];
    const int*   amask = (const int*)d_in[2];
    const float* Wq    = (const float*)d_in[3];
    const float* bq    = (const float*)d_in[4];
    const float* Wk    = (const float*)d_in[5];
    const float* bk    = (const float*)d_in[6];
    const float* Wv    = (const float*)d_in[7];
    const float* bv    = (const float*)d_in[8];
    float* out = (float*)d_out;

    // Workspace (~78 MB):
    //   xT  bf16 [32][1024][512]   Qb  bf16 [32][1024][512]
    //   Kb  bf16 [32*77][512]      Vt  bf16 [32][512][96]
    //   Wqb [512][512]  Wkb/Wvb [512][768]  teb [2464][768]
    unsigned short* xT  = (unsigned short*)d_ws;
    unsigned short* Qb  = xT  + (size_t)BB * HWN * CC;
    unsigned short* Kb  = Qb  + (size_t)BB * HWN * CC;
    unsigned short* Vt  = Kb  + (size_t)BB * MM * CC;
    unsigned short* Wqb = Vt  + (size_t)BB * CC * MPAD;
    unsigned short* Wkb = Wqb + (size_t)CC * CC;
    unsigned short* Wvb = Wkb + (size_t)CC * TXT;
    unsigned short* teb = Wvb + (size_t)CC * TXT;

    prep_kernel<<<dim3(TGRID + CVTOT / 256), 256, 0, stream>>>(
        x, te, Wq, Wk, Wv, xT, teb, Wqb, Wkb, Wvb);
    gemm_all<<<dim3(96 + 512), 512, 0, stream>>>(
        xT, Wqb, bq, Qb, teb, Wkb, bk, Wvb, bv, Kb, Vt);
    attn_mfma<<<dim3(8, NH, BB), 256, 0, stream>>>(Qb, Kb, Vt, amask, out);
}

// Round 9
// 209.514 us; speedup vs baseline: 1.0706x; 1.0706x over previous
//
#include <hip/hip_runtime.h>
#include <math.h>

// Problem constants
#define BB   32
#define CC   512
#define HWN  1024   // H*W
#define MM   77
#define TXT  768
#define NH   8
#define HD   64
#define SCALEF 0.125f   // 1/sqrt(64)
#define MPAD 96          // padded M for PV K-dim (3 x 32)
#define KVROWS (BB*MPAD) // 3072 padded row space for kv gemm
#define PP   104         // Ps pitch in shorts (104*2=208=13*16B, aligned)
#define OSP  132         // Os pitch in floats (multiple of 4 for float4 align)

typedef __attribute__((ext_vector_type(8))) short          bf16x8; // MFMA A/B frag
typedef __attribute__((ext_vector_type(8))) unsigned short us8;
typedef __attribute__((ext_vector_type(4))) float          f32x4;  // MFMA C/D frag

__device__ inline unsigned short f2bf(float f) {
    union { float f; unsigned u; } v; v.f = f;
    unsigned r = v.u + 0x7fff + ((v.u >> 16) & 1);   // RNE
    return (unsigned short)(r >> 16);
}

__device__ inline void gload_lds16(const void* g, void* l) {
    __builtin_amdgcn_global_load_lds(
        (const __attribute__((address_space(1))) void*)g,
        (__attribute__((address_space(3))) void*)l, 16, 0, 0);
}

// ---------------------------------------------------------------------------
// prep: block-id partitioned.
//  bid < 4096 : x[b,c,n] -> xT[b,n,c] bf16 (64x64 LDS transpose tiles)
//  bid >= 4096: flat fp32->bf16 converts of Wq | Wk | Wv | text_emb
// ---------------------------------------------------------------------------
#define TGRID 4096                   // 16 * 8 * 32 transpose blocks
#define CV_WQ 65536                  // 512*512/4 float4s
#define CV_WK 98304                  // 512*768/4
#define CV_WV 98304
#define CV_TE 473088                 // 2464*768/4
#define CVTOT (CV_WQ + CV_WK + CV_WV + CV_TE)   // 735232 = 2872 * 256

__global__ __launch_bounds__(256) void prep_kernel(
    const float* __restrict__ x, const float* __restrict__ te,
    const float* __restrict__ Wq, const float* __restrict__ Wk,
    const float* __restrict__ Wv,
    unsigned short* __restrict__ xT, unsigned short* __restrict__ teb,
    unsigned short* __restrict__ Wqb, unsigned short* __restrict__ Wkb,
    unsigned short* __restrict__ Wvb)
{
    const int bid = blockIdx.x;
    const int t = threadIdx.x;

    if (bid < TGRID) {
        // ---- transpose+convert x ----
        const int nt = bid & 15, ct = (bid >> 4) & 7, b = bid >> 7;
        const int n0 = nt * 64, c0 = ct * 64;
        __shared__ float tile[64][65];
        const float* xb = x + (size_t)b * CC * HWN;
        {
            const int c = t >> 2;
            #pragma unroll
            for (int j = 0; j < 4; ++j) {
                const int f4 = (t & 3) + j * 4;
                const float4 v = *(const float4*)&xb[(size_t)(c0 + c) * HWN + n0 + f4 * 4];
                tile[c][f4 * 4 + 0] = v.x; tile[c][f4 * 4 + 1] = v.y;
                tile[c][f4 * 4 + 2] = v.z; tile[c][f4 * 4 + 3] = v.w;
            }
        }
        __syncthreads();
        unsigned short* xTb = xT + (size_t)b * HWN * CC;
        #pragma unroll
        for (int j = 0; j < 2; ++j) {
            const int n = (t >> 3) + j * 32;
            const int c8 = (t & 7) * 8;
            us8 o;
            #pragma unroll
            for (int i = 0; i < 8; ++i) o[i] = f2bf(tile[c8 + i][n]);
            *(us8*)&xTb[(size_t)(n0 + n) * CC + c0 + c8] = o;
        }
    } else {
        // ---- flat converts ----
        const int idx = (bid - TGRID) * 256 + t;   // float4 index, < CVTOT
        const float* src; unsigned short* dst; int off;
        if (idx < CV_WQ)                    { src = Wq; dst = Wqb; off = idx; }
        else if (idx < CV_WQ + CV_WK)       { src = Wk; dst = Wkb; off = idx - CV_WQ; }
        else if (idx < CV_WQ + CV_WK + CV_WV) { src = Wv; dst = Wvb; off = idx - CV_WQ - CV_WK; }
        else                                { src = te; dst = teb; off = idx - CV_WQ - CV_WK - CV_WV; }
        const float4 v = ((const float4*)src)[off];
        ushort4 o;
        o.x = f2bf(v.x); o.y = f2bf(v.y); o.z = f2bf(v.z); o.w = f2bf(v.w);
        ((ushort4*)dst)[off] = o;
    }
}

// ---------------------------------------------------------------------------
// gemm_all: merged Q-GEMM + K/V-GEMM, 128x128 tiles, BK=32, 16B global_load_lds
// staging, 4 waves (2x2), 4x4 16x16x32 MFMA tiles per wave.
// 3-buffer LDS, 2-deep prefetch, counted vmcnt with WAIT-BEFORE-BARRIER:
//   per iter: s_waitcnt vmcnt(4) -> s_barrier -> stage(k+2) -> compute k
// (PROVEN r6 config: 46.6 us, 124 VGPR, no spill. Round-8 lesson: the
//  256x128/8-wave variant with __launch_bounds__(512,4) forced a 128-reg
//  unified VGPR+AGPR cap -> 64 arch VGPRs -> scratch spill (WRITE_SIZE
//  doubled). Do NOT raise occupancy targets past the acc+frag register
//  arithmetic: acc 64 AGPR + frags 64 VGPR + addressing needs ~190 total.)
//  bid < 192           : K/V = teb . W^T + bias     -> Kb / Vt (transposed)
//  bid >= 192          : Q = xT . Wqb^T + bq        -> Qb bf16 [32768][512]
// (K/V first: 24 K-iters vs Q's 16 -> longest blocks launch first)
// ---------------------------------------------------------------------------
__global__ __launch_bounds__(256) void gemm_all(
    const unsigned short* __restrict__ xT, const unsigned short* __restrict__ Wqb,
    const float* __restrict__ bq, unsigned short* __restrict__ Qb,
    const unsigned short* __restrict__ teb,
    const unsigned short* __restrict__ Wkb, const float* __restrict__ bk,
    const unsigned short* __restrict__ Wvb, const float* __restrict__ bv,
    unsigned short* __restrict__ Kb, unsigned short* __restrict__ Vt)
{
    const int bid = blockIdx.x;
    __shared__ unsigned short As[3][128 * 32];
    __shared__ unsigned short Bs[3][128 * 32];
    const int t = threadIdx.x;
    const int lane = t & 63, w = t >> 6;
    const int wr = w >> 1, wc = w & 1;
    const int lm = lane & 15, quad = lane >> 4;
    const int lrow = lane >> 2, lk = (lane & 3) * 8;

    const unsigned short *gA0, *gA1, *gB0, *gB1;
    int kIters, mode, row0, co0;

    if (bid >= 192) {
        const int qb = bid - 192;
        mode = 0;
        const int rt = qb & 255, ct = qb >> 8;
        row0 = rt * 128; co0 = ct * 128;
        kIters = CC / 32;
        gA0 = xT  + (size_t)(row0 + (w * 2 + 0) * 16 + lrow) * CC + lk;
        gA1 = xT  + (size_t)(row0 + (w * 2 + 1) * 16 + lrow) * CC + lk;
        gB0 = Wqb + (size_t)(co0 + (w * 2 + 0) * 16 + lrow) * CC + lk;
        gB1 = Wqb + (size_t)(co0 + (w * 2 + 1) * 16 + lrow) * CC + lk;
    } else {
        const int id = bid;                 // 0..191
        const int rt = id % 24, cc = id / 24;
        const int isV = (cc >= 4);
        mode = isV ? 2 : 1;
        row0 = rt * 128; co0 = (cc & 3) * 128;
        kIters = TXT / 32;
        const unsigned short* Wb = isV ? Wvb : Wkb;
        const int rp0 = row0 + (w * 2 + 0) * 16 + lrow;
        const int rp1 = row0 + (w * 2 + 1) * 16 + lrow;
        const int b0i = rp0 / MPAD, m0i = min(rp0 % MPAD, MM - 1);
        const int b1i = rp1 / MPAD, m1i = min(rp1 % MPAD, MM - 1);
        gA0 = teb + (size_t)(b0i * MM + m0i) * TXT + lk;
        gA1 = teb + (size_t)(b1i * MM + m1i) * TXT + lk;
        gB0 = Wb + (size_t)(co0 + (w * 2 + 0) * 16 + lrow) * TXT + lk;
        gB1 = Wb + (size_t)(co0 + (w * 2 + 1) * 16 + lrow) * TXT + lk;
    }

    f32x4 acc[4][4] = {};

    const int lA0 = (w * 2 + 0) * 512, lA1 = (w * 2 + 1) * 512;

    // prologue: stage tile 0 -> buf0, tile 1 -> buf1 (8 loads outstanding)
    gload_lds16(gA0, &As[0][lA0]);
    gload_lds16(gA1, &As[0][lA1]);
    gload_lds16(gB0, &Bs[0][lA0]);
    gload_lds16(gB1, &Bs[0][lA1]);
    gload_lds16(gA0 + 32, &As[1][lA0]);
    gload_lds16(gA1 + 32, &As[1][lA1]);
    gload_lds16(gB0 + 32, &Bs[1][lA0]);
    gload_lds16(gB1 + 32, &Bs[1][lA1]);

    int cb = 0;                       // buffer holding tile k
    for (int k = 0; k < kIters; ++k) {
        // retire MY tile-k loads (tile k+1's 4 stay in flight), THEN join:
        // after the barrier, every wave's tile-k rows are in LDS.
        if (k + 1 < kIters) {
            asm volatile("s_waitcnt vmcnt(4)" ::: "memory");
        } else {
            asm volatile("s_waitcnt vmcnt(0)" ::: "memory");
        }
        __builtin_amdgcn_s_barrier();
        __builtin_amdgcn_sched_barrier(0);

        // stage tile k+2 into buf (cb+2)%3 (tile k-1's buffer; all waves'
        // reads of it completed before they arrived at the barrier above)
        if (k + 2 < kIters) {
            const int nb = (cb >= 1) ? cb - 1 : 2;   // (cb+2)%3
            gload_lds16(gA0 + (k + 2) * 32, &As[nb][lA0]);
            gload_lds16(gA1 + (k + 2) * 32, &As[nb][lA1]);
            gload_lds16(gB0 + (k + 2) * 32, &Bs[nb][lA0]);
            gload_lds16(gB1 + (k + 2) * 32, &Bs[nb][lA1]);
        }

        bf16x8 a[4], bfr[4];
        #pragma unroll
        for (int i = 0; i < 4; ++i)
            a[i] = *(const bf16x8*)&As[cb][(wr * 64 + i * 16 + lm) * 32 + quad * 8];
        #pragma unroll
        for (int i = 0; i < 4; ++i)
            bfr[i] = *(const bf16x8*)&Bs[cb][(wc * 64 + i * 16 + lm) * 32 + quad * 8];
        #pragma unroll
        for (int mi = 0; mi < 4; ++mi)
            #pragma unroll
            for (int ni = 0; ni < 4; ++ni)
                acc[mi][ni] = __builtin_amdgcn_mfma_f32_16x16x32_bf16(
                    a[mi], bfr[ni], acc[mi][ni], 0, 0, 0);

        cb = (cb >= 2) ? 0 : cb + 1;
    }

    if (mode == 0) {
        #pragma unroll
        for (int ni = 0; ni < 4; ++ni) {
            const int col = co0 + wc * 64 + ni * 16 + lm;
            const float bias = bq[col];
            #pragma unroll
            for (int mi = 0; mi < 4; ++mi) {
                #pragma unroll
                for (int j = 0; j < 4; ++j) {
                    const int row = row0 + wr * 64 + mi * 16 + quad * 4 + j;
                    Qb[(size_t)row * CC + col] = f2bf(acc[mi][ni][j] + bias);
                }
            }
        }
    } else {
        const float* bias_p = (mode == 2) ? bv : bk;
        #pragma unroll
        for (int ni = 0; ni < 4; ++ni) {
            const int col = co0 + wc * 64 + ni * 16 + lm;
            const float bias = bias_p[col];
            #pragma unroll
            for (int mi = 0; mi < 4; ++mi) {
                #pragma unroll
                for (int j = 0; j < 4; ++j) {
                    const int row = row0 + wr * 64 + mi * 16 + quad * 4 + j;
                    const int bo = row / MPAD, mo = row % MPAD;
                    const unsigned short hv = f2bf(acc[mi][ni][j] + bias);
                    if (mode == 2) {
                        Vt[((size_t)bo * CC + col) * MPAD + mo] = hv;
                    } else if (mo < MM) {
                        Kb[((size_t)bo * MM + mo) * CC + col] = hv;
                    }
                }
            }
        }
    }
}

// ---------------------------------------------------------------------------
// MFMA attention: block = (128 Q rows, head h, batch b). QK^T via mfma,
// softmax in C-layout regs, exp(P)->LDS (A-layout bf16), PV via mfma,
// epilogue transposed through LDS -> coalesced float4 stores along n.
// ---------------------------------------------------------------------------
__global__ __launch_bounds__(256) void attn_mfma(
    const unsigned short* __restrict__ Qb, const unsigned short* __restrict__ Kb,
    const unsigned short* __restrict__ Vt, const int* __restrict__ amask,
    float* __restrict__ out)
{
    const int ntile = blockIdx.x;   // 0..7
    const int h     = blockIdx.y;   // 0..7
    const int b     = blockIdx.z;   // 0..31
    const int row0  = ntile * 128;

    __shared__ char smem[64 * OSP * 4];   // Ps then Os (unioned)
    __shared__ float msk[80];
    unsigned short* Ps = (unsigned short*)smem;
    float* Os = (float*)smem;

    const int t = threadIdx.x;
    const int w = t >> 6, lane = t & 63;
    const int lm = lane & 15, quad = lane >> 4;

    {
        const int r = t >> 1, off = 80 + (t & 1) * 8;
        us8 z = {0, 0, 0, 0, 0, 0, 0, 0};
        *(us8*)&Ps[r * PP + off] = z;
    }
    if (t < 80) msk[t] = (t < MM && amask[b * MM + t] != 0) ? 0.f : -INFINITY;
    __syncthreads();

    // ---- Phase 1: scores = Q K^T ----
    f32x4 s[2][5] = {};
    const unsigned short* qbase = Qb + ((size_t)b * HWN + row0) * CC + h * HD;
    const unsigned short* kbase = Kb + (size_t)b * MM * CC + h * HD;
    #pragma unroll
    for (int ks = 0; ks < 2; ++ks) {
        bf16x8 a[2], kf[5];
        #pragma unroll
        for (int mt = 0; mt < 2; ++mt)
            a[mt] = *(const bf16x8*)&qbase[(size_t)((w * 2 + mt) * 16 + lm) * CC + ks * 32 + quad * 8];
        #pragma unroll
        for (int n = 0; n < 5; ++n) {
            const int kr = min(n * 16 + lm, MM - 1);
            kf[n] = *(const bf16x8*)&kbase[(size_t)kr * CC + ks * 32 + quad * 8];
        }
        #pragma unroll
        for (int mt = 0; mt < 2; ++mt)
            #pragma unroll
            for (int n = 0; n < 5; ++n)
                s[mt][n] = __builtin_amdgcn_mfma_f32_16x16x32_bf16(a[mt], kf[n], s[mt][n], 0, 0, 0);
    }

    // ---- Phase 2: masked softmax per row ----
    float inv[2][4];
    #pragma unroll
    for (int mt = 0; mt < 2; ++mt) {
        #pragma unroll
        for (int j = 0; j < 4; ++j) {
            float v[5];
            #pragma unroll
            for (int n = 0; n < 5; ++n)
                v[n] = s[mt][n][j] * SCALEF + msk[n * 16 + lm];
            float mx = fmaxf(fmaxf(fmaxf(v[0], v[1]), fmaxf(v[2], v[3])), v[4]);
            mx = fmaxf(mx, __shfl_xor(mx, 1, 64));
            mx = fmaxf(mx, __shfl_xor(mx, 2, 64));
            mx = fmaxf(mx, __shfl_xor(mx, 4, 64));
            mx = fmaxf(mx, __shfl_xor(mx, 8, 64));
            float sum = 0.f;
            #pragma unroll
            for (int n = 0; n < 5; ++n) { v[n] = __expf(v[n] - mx); sum += v[n]; }
            sum += __shfl_xor(sum, 1, 64);
            sum += __shfl_xor(sum, 2, 64);
            sum += __shfl_xor(sum, 4, 64);
            sum += __shfl_xor(sum, 8, 64);
            inv[mt][j] = 1.0f / sum;
            const int mrow = (w * 2 + mt) * 16 + quad * 4 + j;
            #pragma unroll
            for (int n = 0; n < 5; ++n)
                Ps[mrow * PP + n * 16 + lm] = f2bf(v[n]);
        }
    }
    __syncthreads();

    // ---- Phase 3: O = P V ----
    f32x4 o[2][4] = {};
    const unsigned short* vbase = Vt + ((size_t)b * CC + h * HD) * MPAD;
    #pragma unroll
    for (int ks = 0; ks < 3; ++ks) {
        bf16x8 a[2], vf[4];
        #pragma unroll
        for (int mt = 0; mt < 2; ++mt)
            a[mt] = *(const bf16x8*)&Ps[((w * 2 + mt) * 16 + lm) * PP + ks * 32 + quad * 8];
        #pragma unroll
        for (int n = 0; n < 4; ++n)
            vf[n] = *(const bf16x8*)&vbase[(size_t)(n * 16 + lm) * MPAD + ks * 32 + quad * 8];
        #pragma unroll
        for (int mt = 0; mt < 2; ++mt)
            #pragma unroll
            for (int n = 0; n < 4; ++n)
                o[mt][n] = __builtin_amdgcn_mfma_f32_16x16x32_bf16(a[mt], vf[n], o[mt][n], 0, 0, 0);
    }
    __syncthreads();   // Ps fully consumed; smem becomes Os

    // ---- Epilogue 1: scaled O -> Os[col][r], float4 LDS writes ----
    #pragma unroll
    for (int mt = 0; mt < 2; ++mt) {
        #pragma unroll
        for (int n = 0; n < 4; ++n) {
            const int col = n * 16 + lm;
            const int r0 = (w * 2 + mt) * 16 + quad * 4;
            float4 st;
            st.x = o[mt][n][0] * inv[mt][0];
            st.y = o[mt][n][1] * inv[mt][1];
            st.z = o[mt][n][2] * inv[mt][2];
            st.w = o[mt][n][3] * inv[mt][3];
            *(float4*)&Os[col * OSP + r0] = st;
        }
    }
    __syncthreads();

    // ---- Epilogue 2: coalesced float4 stores, contiguous in n ----
    float* obase = out + ((size_t)b * CC + h * HD) * HWN + row0;
    #pragma unroll
    for (int p = 0; p < 8; ++p) {
        const int idx = p * 256 + t;
        const int col = idx >> 5;
        const int r4  = idx & 31;
        const float4 v = *(const float4*)&Os[col * OSP + r4 * 4];
        *(float4*)&obase[(size_t)col * HWN + r4 * 4] = v;
    }
}

extern "C" void kernel_launch(void* const* d_in, const int* in_sizes, int n_in,
                              void* d_out, int out_size, void* d_ws, size_t ws_size,
                              hipStream_t stream)
{
    const float* x     = (const float*)d_in[0];
    const float* te    = (const float*)d_in[1];
    const int*   amask = (const int*)d_in[2];
    const float* Wq    = (const float*)d_in[3];
    const float* bq    = (const float*)d_in[4];
    const float* Wk    = (const float*)d_in[5];
    const float* bk    = (const float*)d_in[6];
    const float* Wv    = (const float*)d_in[7];
    const float* bv    = (const float*)d_in[8];
    float* out = (float*)d_out;

    // Workspace (~78 MB):
    //   xT  bf16 [32][1024][512]   Qb  bf16 [32][1024][512]
    //   Kb  bf16 [32*77][512]      Vt  bf16 [32][512][96]
    //   Wqb [512][512]  Wkb/Wvb [512][768]  teb [2464][768]
    unsigned short* xT  = (unsigned short*)d_ws;
    unsigned short* Qb  = xT  + (size_t)BB * HWN * CC;
    unsigned short* Kb  = Qb  + (size_t)BB * HWN * CC;
    unsigned short* Vt  = Kb  + (size_t)BB * MM * CC;
    unsigned short* Wqb = Vt  + (size_t)BB * CC * MPAD;
    unsigned short* Wkb = Wqb + (size_t)CC * CC;
    unsigned short* Wvb = Wkb + (size_t)CC * TXT;
    unsigned short* teb = Wvb + (size_t)CC * TXT;

    prep_kernel<<<dim3(TGRID + CVTOT / 256), 256, 0, stream>>>(
        x, te, Wq, Wk, Wv, xT, teb, Wqb, Wkb, Wvb);
    gemm_all<<<dim3(1024 + 192), 256, 0, stream>>>(
        xT, Wqb, bq, Qb, teb, Wkb, bk, Wvb, bv, Kb, Vt);
    attn_mfma<<<dim3(8, NH, BB), 256, 0, stream>>>(Qb, Kb, Vt, amask, out);
}